// Round 1
// baseline (1435.635 us; speedup 1.0000x reference)
//
#include <hip/hip_runtime.h>

// DBRX attention layer: B=1, T=2048, D_MODEL=6144, NH=48, NKV=8, HD=128,
// rope_base=5e5 full-dim, clamp +-8, causal, f32 in/out, bf16 MFMA compute.

typedef __attribute__((ext_vector_type(8))) short bf16x8;
typedef __attribute__((ext_vector_type(4))) float f32x4;

__device__ inline short f2bf(float f) {
  union { float f; unsigned u; } v; v.f = f;
  unsigned r = v.u + 0x7fffu + ((v.u >> 16) & 1u);  // round-to-nearest-even
  return (short)(r >> 16);
}

// ---------------- f32 -> bf16 convert (8 elems/thread) ----------------
__global__ void cvt_bf16(const float* __restrict__ in, short* __restrict__ out, int n8) {
  int i = blockIdx.x * 256 + threadIdx.x;
  if (i >= n8) return;
  const float4* p = (const float4*)in;
  float4 a = p[2 * i], b = p[2 * i + 1];
  bf16x8 r;
  r[0] = f2bf(a.x); r[1] = f2bf(a.y); r[2] = f2bf(a.z); r[3] = f2bf(a.w);
  r[4] = f2bf(b.x); r[5] = f2bf(b.y); r[6] = f2bf(b.z); r[7] = f2bf(b.w);
  *((bf16x8*)out + i) = r;
}

// ---------------- bf16 GEMM, B^T input (m97 structure) ----------------
// A: MxK row-major bf16, B: NxK row-major bf16 (i.e. B^T), C: MxN f32.
// 128x128 tile, BK=32, 4 waves each computing 64x64 via 4x4 16x16x32 MFMAs.
__device__ inline void gload_lds16(const short* g, short* l) {
  __builtin_amdgcn_global_load_lds(
      (const __attribute__((address_space(1))) void*)g,
      (__attribute__((address_space(3))) void*)l, 16, 0, 0);
}

__global__ __launch_bounds__(256) void gemm_bt(const short* __restrict__ A,
                                               const short* __restrict__ B,
                                               float* __restrict__ C,
                                               int M, int N, int K) {
  __shared__ short As[128 * 32];
  __shared__ short Bs[128 * 32];
  int tid = threadIdx.x;
  int wave = tid >> 6, lane = tid & 63;
  int lm = lane & 15, quad = lane >> 4;
  int bm = blockIdx.y * 128, bn = blockIdx.x * 128;
  int wm = (wave >> 1) * 64, wn = (wave & 1) * 64;
  f32x4 acc[4][4] = {};
  for (int k0 = 0; k0 < K; k0 += 32) {
    // stage A tile 128x32 (8KB): 512 16B-chunks; chunk c -> row c>>2, k (c&3)*8.
    // LDS dest must be wave-uniform base + lane*16: chunk c = i*256 + wave*64 + lane.
#pragma unroll
    for (int i = 0; i < 2; ++i) {
      int c = tid + i * 256;
      gload_lds16(A + (size_t)(bm + (c >> 2)) * K + k0 + (c & 3) * 8,
                  As + (i * 256 + wave * 64) * 8);
    }
#pragma unroll
    for (int i = 0; i < 2; ++i) {
      int c = tid + i * 256;
      gload_lds16(B + (size_t)(bn + (c >> 2)) * K + k0 + (c & 3) * 8,
                  Bs + (i * 256 + wave * 64) * 8);
    }
    __syncthreads();  // drains vmcnt (global_load_lds) per compiler semantics
    bf16x8 a[4], b[4];
#pragma unroll
    for (int r = 0; r < 4; ++r)
      a[r] = *(const bf16x8*)(As + (wm + r * 16 + lm) * 32 + quad * 8);
#pragma unroll
    for (int c = 0; c < 4; ++c)
      b[c] = *(const bf16x8*)(Bs + (wn + c * 16 + lm) * 32 + quad * 8);
#pragma unroll
    for (int r = 0; r < 4; ++r)
#pragma unroll
      for (int c = 0; c < 4; ++c)
        acc[r][c] = __builtin_amdgcn_mfma_f32_16x16x32_bf16(a[r], b[c], acc[r][c], 0, 0, 0);
    __syncthreads();
  }
  // C/D layout: col = lane&15, row = quad*4 + reg  (m89-verified)
#pragma unroll
  for (int r = 0; r < 4; ++r)
#pragma unroll
    for (int c = 0; c < 4; ++c)
#pragma unroll
      for (int e = 0; e < 4; ++e)
        C[(size_t)(bm + wm + r * 16 + quad * 4 + e) * N + (bn + wn + c * 16 + lm)] =
            acc[r][c][e];
}

// ---------------- RoPE + clamp + split/cast ----------------
// qkv f32 [2048][8192] -> Qb[48][2048][128], Kb[8][2048][128], Vtb[8][128][2048] (bf16)
__global__ void rope_split(const float* __restrict__ qkv, short* __restrict__ Qb,
                           short* __restrict__ Kb, short* __restrict__ Vtb) {
  int idx = blockIdx.x * 256 + threadIdx.x;  // one thread per (t, element-pair)
  int t = idx >> 12;                          // 4096 pairs per row
  int p = idx & 4095;
  int o = p * 2;
  float2 ab = *(const float2*)(qkv + (size_t)t * 8192 + o);
  float a = ab.x, b = ab.y;
  if (o < 7168) {  // q and k get rope; v does not
    int d = o & 127;  // within-head offset (even); pair index i = d/2, exponent 2i/128 = d/128
    float ang = (float)t * exp2f((float)d * (-18.931568569324174f / 128.0f));
    float s, c;
    sincosf(ang, &s, &c);  // accurate range reduction (args up to ~2047 rad)
    float a2 = a * c - b * s;
    float b2 = a * s + b * c;
    a = a2; b = b2;
  }
  a = fminf(8.0f, fmaxf(-8.0f, a));
  b = fminf(8.0f, fmaxf(-8.0f, b));
  short sa = f2bf(a), sb = f2bf(b);
  if (o < 6144) {
    int h = o >> 7, d = o & 127;
    short* q = Qb + (size_t)(h * 2048 + t) * 128 + d;
    q[0] = sa; q[1] = sb;
  } else if (o < 7168) {
    int oo = o - 6144; int h = oo >> 7, d = oo & 127;
    short* k = Kb + (size_t)(h * 2048 + t) * 128 + d;
    k[0] = sa; k[1] = sb;
  } else {
    int oo = o - 7168; int h = oo >> 7, d = oo & 127;
    Vtb[(size_t)(h * 128 + d) * 2048 + t]     = sa;  // transposed store for PV B-frags
    Vtb[(size_t)(h * 128 + d + 1) * 2048 + t] = sb;
  }
}

// ---------------- flash attention (causal, GQA) ----------------
// grid: (32 m-tiles of 64 rows, 48 heads), 256 thr. Wave w owns q rows mtile*64+w*16..+15.
// Out: attn [2048][6144] bf16 row-major (input A of out-projection GEMM).
__global__ __launch_bounds__(256) void flash_attn(const short* __restrict__ Q,
                                                  const short* __restrict__ K,
                                                  const short* __restrict__ Vt,
                                                  short* __restrict__ Ob) {
  __shared__ short Ks[64 * 136];    // K tile [64 kv][128 d], +8 pad (2-way conflicts only)
  __shared__ short Vs[128 * 72];    // V^T tile [128 d][64 kv], +8 pad
  __shared__ short Ps[4][16 * 72];  // per-wave P round-trip (C-layout -> A-layout)
  int mtile = blockIdx.x, h = blockIdx.y;
  int hk = h / 6;  // GQA: jnp.repeat -> kv head = h / (48/8)
  int tid = threadIdx.x, wave = tid >> 6, lane = tid & 63;
  int lm = lane & 15, quad = lane >> 4;
  int qrow0 = mtile * 64 + wave * 16;
  // Q fragments (A-layout: m=lane&15, k=quad*8+j), kept in registers across KV loop
  bf16x8 qf[4];
#pragma unroll
  for (int kc = 0; kc < 4; ++kc)
    qf[kc] = *(const bf16x8*)(Q + (size_t)(h * 2048 + qrow0 + lm) * 128 + kc * 32 + quad * 8);
  f32x4 o_acc[8] = {};
  float m_run[4] = {-1e30f, -1e30f, -1e30f, -1e30f};
  float l_run[4] = {0.f, 0.f, 0.f, 0.f};
  const float sc = 0.08838834764831845f;  // 1/sqrt(128)
  int nkv = mtile + 1;                    // causal: kv blocks 0..mtile
  for (int kb = 0; kb < nkv; ++kb) {
    int kv0 = kb * 64;
    __syncthreads();  // previous iter's LDS reads done before restaging
#pragma unroll
    for (int i = 0; i < 4; ++i) {  // stage K [64][128]
      int c = tid + i * 256;
      int r = c >> 4, ko = (c & 15) * 8;
      *(bf16x8*)(Ks + r * 136 + ko) =
          *(const bf16x8*)(K + (size_t)(hk * 2048 + kv0 + r) * 128 + ko);
    }
#pragma unroll
    for (int i = 0; i < 4; ++i) {  // stage V^T [128][64]
      int c = tid + i * 256;
      int d = c >> 3, to = (c & 7) * 8;
      *(bf16x8*)(Vs + d * 72 + to) =
          *(const bf16x8*)(Vt + (size_t)(hk * 128 + d) * 2048 + kv0 + to);
    }
    __syncthreads();
    // S = Q K^T : 4 col-tiles x 4 k-chunks
    f32x4 s[4];
#pragma unroll
    for (int ct = 0; ct < 4; ++ct) {
      f32x4 acc = {};
#pragma unroll
      for (int kc = 0; kc < 4; ++kc) {
        bf16x8 bfr = *(const bf16x8*)(Ks + (ct * 16 + lm) * 136 + kc * 32 + quad * 8);
        acc = __builtin_amdgcn_mfma_f32_16x16x32_bf16(qf[kc], bfr, acc, 0, 0, 0);
      }
      s[ct] = acc;
    }
    // scale + causal mask (S element: row=qrow0+quad*4+e, col=kv0+ct*16+lm)
#pragma unroll
    for (int ct = 0; ct < 4; ++ct) {
      int col = kv0 + ct * 16 + lm;
#pragma unroll
      for (int e = 0; e < 4; ++e) {
        int row = qrow0 + quad * 4 + e;
        float v = s[ct][e] * sc;
        s[ct][e] = (col > row) ? -1e30f : v;
      }
    }
    // online softmax: row stats live replicated across the quad's 16 lanes
    float mx[4];
#pragma unroll
    for (int e = 0; e < 4; ++e)
      mx[e] = fmaxf(fmaxf(s[0][e], s[1][e]), fmaxf(s[2][e], s[3][e]));
#pragma unroll
    for (int off = 1; off < 16; off <<= 1)
#pragma unroll
      for (int e = 0; e < 4; ++e) mx[e] = fmaxf(mx[e], __shfl_xor(mx[e], off, 64));
    float alpha[4];
#pragma unroll
    for (int e = 0; e < 4; ++e) {
      float mn = fmaxf(m_run[e], mx[e]);
      alpha[e] = __expf(m_run[e] - mn);
      m_run[e] = mn;
    }
    float rs[4] = {0.f, 0.f, 0.f, 0.f};
#pragma unroll
    for (int ct = 0; ct < 4; ++ct)
#pragma unroll
      for (int e = 0; e < 4; ++e) {
        float pv = __expf(s[ct][e] - m_run[e]);  // masked -> exp(-1e30-m) == 0
        s[ct][e] = pv;
        rs[e] += pv;
      }
#pragma unroll
    for (int off = 1; off < 16; off <<= 1)
#pragma unroll
      for (int e = 0; e < 4; ++e) rs[e] += __shfl_xor(rs[e], off, 64);
#pragma unroll
    for (int e = 0; e < 4; ++e) l_run[e] = l_run[e] * alpha[e] + rs[e];
#pragma unroll
    for (int ot = 0; ot < 8; ++ot)
#pragma unroll
      for (int e = 0; e < 4; ++e) o_acc[ot][e] *= alpha[e];
    // P: C-layout regs -> LDS -> A-layout frags (wave-private buffer, no barrier)
    short* pw = &Ps[wave][0];
#pragma unroll
    for (int ct = 0; ct < 4; ++ct)
#pragma unroll
      for (int e = 0; e < 4; ++e)
        pw[(quad * 4 + e) * 72 + ct * 16 + lm] = f2bf(s[ct][e]);
#pragma unroll
    for (int kc = 0; kc < 2; ++kc) {
      bf16x8 afr = *(const bf16x8*)(pw + lm * 72 + kc * 32 + quad * 8);
#pragma unroll
      for (int ot = 0; ot < 8; ++ot) {
        bf16x8 bfr = *(const bf16x8*)(Vs + (ot * 16 + lm) * 72 + kc * 32 + quad * 8);
        o_acc[ot] = __builtin_amdgcn_mfma_f32_16x16x32_bf16(afr, bfr, o_acc[ot], 0, 0, 0);
      }
    }
  }
  // epilogue: O / l, write [t][h*128+d] bf16
#pragma unroll
  for (int ot = 0; ot < 8; ++ot)
#pragma unroll
    for (int e = 0; e < 4; ++e) {
      float v = o_acc[ot][e] / l_run[e];
      Ob[(size_t)(qrow0 + quad * 4 + e) * 6144 + h * 128 + ot * 16 + lm] = f2bf(v);
    }
}

// ---------------- launch ----------------
extern "C" void kernel_launch(void* const* d_in, const int* in_sizes, int n_in,
                              void* d_out, int out_size, void* d_ws, size_t ws_size,
                              hipStream_t stream) {
  const float* x     = (const float*)d_in[0];
  // d_in[1] = causal_mask: implemented analytically, unused
  const float* w_qkv = (const float*)d_in[2];
  const float* w_out = (const float*)d_in[3];
  float* out = (float*)d_out;

  // workspace layout (bytes):
  short* xb    = (short*)d_ws;                       // 2048*6144 bf16
  short* wqkvb = xb + (size_t)2048 * 6144;           // 8192*6144 bf16
  short* woutb = wqkvb + (size_t)8192 * 6144;        // 6144*6144 bf16
  float* qkvf  = (float*)(woutb + (size_t)6144 * 6144);  // 2048*8192 f32
  short* Qb    = (short*)(qkvf + (size_t)2048 * 8192);   // 48*2048*128
  short* Kb    = Qb + (size_t)48 * 2048 * 128;           // 8*2048*128
  short* Vtb   = Kb + (size_t)8 * 2048 * 128;            // 8*128*2048 (transposed)
  short* attnb = Vtb + (size_t)8 * 128 * 2048;           // 2048*6144

  cvt_bf16<<<(2048 * 6144 / 8) / 256, 256, 0, stream>>>(x, xb, 2048 * 6144 / 8);
  cvt_bf16<<<(8192 * 6144 / 8) / 256, 256, 0, stream>>>(w_qkv, wqkvb, 8192 * 6144 / 8);
  cvt_bf16<<<(6144 * 6144 / 8) / 256, 256, 0, stream>>>(w_out, woutb, 6144 * 6144 / 8);

  gemm_bt<<<dim3(8192 / 128, 2048 / 128), 256, 0, stream>>>(xb, wqkvb, qkvf, 2048, 8192, 6144);

  rope_split<<<(2048 * 4096) / 256, 256, 0, stream>>>(qkvf, Qb, Kb, Vtb);

  flash_attn<<<dim3(32, 48), 256, 0, stream>>>(Qb, Kb, Vtb, attnb);

  gemm_bt<<<dim3(6144 / 128, 2048 / 128), 256, 0, stream>>>(attnb, woutb, out, 2048, 6144, 6144);
}